// Round 2
// baseline (492.536 us; speedup 1.0000x reference)
//
#include <hip/hip_runtime.h>
#include <stdint.h>

typedef __attribute__((ext_vector_type(4))) int   i32x4;
typedef __attribute__((ext_vector_type(16))) int  i32x16;

#define TM 256
#define TN 128
#define BKB 128    // K-bytes per pipeline step; group = 256 = 2 steps
#define NSTAGE 3   // triple-buffered LDS -> counted vmcnt(6) across barriers

// ---------- helpers ----------

// async global -> LDS, 16 bytes per lane. LDS dest = wave-uniform base + lane*16.
__device__ __forceinline__ void async16(const void* g, void* l) {
  __builtin_amdgcn_global_load_lds(
      (__attribute__((address_space(1))) void*)g,
      (__attribute__((address_space(3))) void*)l,
      16, 0, 0);
}

__device__ __forceinline__ int swz(int r) { return (r ^ (r >> 3)) & 7; }

// ---------- fused prep kernel ----------
// blocks [0, M)      : per-token dynamic quant -> int8 Aq + tokScale/tokZp
// blocks [M, M+OUT)  : weight prep: Wq = w - zero (int8), T[n] = sum_k s*(w-z)
__global__ __launch_bounds__(256) void prep_kernel(
    const float* __restrict__ x, int8_t* __restrict__ Aq,
    float* __restrict__ tokScale, float* __restrict__ tokZp,
    const int* __restrict__ W, const float* __restrict__ scales,
    const float* __restrict__ zeros, int8_t* __restrict__ Wq,
    float* __restrict__ T, int K, int M, int gpr, int G)
{
  const int t = threadIdx.x;
  const int wave = t >> 6, lane = t & 63;
  __shared__ float sA[4], sB[4];

  if ((int)blockIdx.x < M) {
    const int token = blockIdx.x;
    const float4* xin = (const float4*)(x + (size_t)token * K);
    float4 v[4];
#pragma unroll
    for (int j = 0; j < 4; ++j) v[j] = xin[t + 256 * j];

    float mn = v[0].x, mx = v[0].x;
#pragma unroll
    for (int j = 0; j < 4; ++j) {
      mn = fminf(mn, fminf(fminf(v[j].x, v[j].y), fminf(v[j].z, v[j].w)));
      mx = fmaxf(mx, fmaxf(fmaxf(v[j].x, v[j].y), fmaxf(v[j].z, v[j].w)));
    }
#pragma unroll
    for (int off = 32; off >= 1; off >>= 1) {
      mn = fminf(mn, __shfl_xor(mn, off));
      mx = fmaxf(mx, __shfl_xor(mx, off));
    }
    if (lane == 0) { sA[wave] = mn; sB[wave] = mx; }
    __syncthreads();
    mn = fminf(fminf(sA[0], sA[1]), fminf(sA[2], sA[3]));
    mx = fmaxf(fmaxf(sB[0], sB[1]), fmaxf(sB[2], sB[3]));

    mn = fminf(mn, 0.0f);
    mx = fmaxf(mx, 0.0f);
    const float scale = fmaxf((mx - mn) / 255.0f, 1.1920929e-07f);
    float zp = -128.0f - rintf(mn / scale);
    zp = fminf(fmaxf(zp, -128.0f), 127.0f);
    const float rs = 1.0f / scale;

    uint32_t* dst = (uint32_t*)(Aq + (size_t)token * K);
#pragma unroll
    for (int j = 0; j < 4; ++j) {
      float e[4] = {v[j].x, v[j].y, v[j].z, v[j].w};
      uint32_t pk = 0;
#pragma unroll
      for (int i = 0; i < 4; ++i) {
        float q = rintf(e[i] * rs) + zp;
        q = fminf(fmaxf(q, -128.0f), 127.0f);
        pk |= ((uint32_t)(int)q & 0xFFu) << (8 * i);
      }
      dst[t + 256 * j] = pk;
    }
    if (t == 0) { tokScale[token] = scale; tokZp[token] = zp; }
  } else {
    const int row = blockIdx.x - M;
    const int4* wp = (const int4*)(W + (size_t)row * K);
    uint32_t* dst = (uint32_t*)(Wq + (size_t)row * K);

    float partial = 0.0f;
#pragma unroll
    for (int j = 0; j < 4; ++j) {
      const int idx = t + 256 * j;
      const int g = (idx * 4) / G;
      const float s = scales[(size_t)row * gpr + g];
      const int zi = (int)zeros[(size_t)row * gpr + g];
      int4 w4 = wp[idx];
      const int a = w4.x - zi, b = w4.y - zi, c = w4.z - zi, d = w4.w - zi;
      dst[idx] = ((uint32_t)a & 0xFFu) | (((uint32_t)b & 0xFFu) << 8)
               | (((uint32_t)c & 0xFFu) << 16) | (((uint32_t)d & 0xFFu) << 24);
      partial += s * (float)(a + b + c + d);
    }
#pragma unroll
    for (int off = 32; off >= 1; off >>= 1) partial += __shfl_xor(partial, off);
    if (lane == 0) sA[wave] = partial;
    __syncthreads();
    if (t == 0) T[row] = (sA[0] + sA[1]) + (sA[2] + sA[3]);
  }
}

// ---------- int8 MFMA GEMM: 3-stage, counted-vmcnt, 4-phase fine interleave ----------
// out[m,n] = ts_m * ( sum_g s[n,g]*dot_g[m,n] - zp_m*T[n] ) + bias[n]
//
// 256x128 tile, 512 threads (8 waves = 4M x 2N, 64x64/wave, 2x2 frags of 32x32x32).
// Each 128-B K-step = 4 phases (one per MFMA k-slice):
//   { 4x ds_read_b128 ; 1-2 global_load_lds (tile t+2) ; s_barrier ; lgkmcnt(0) ;
//     setprio(1) 4x MFMA setprio(0) ; s_barrier }
// The ONLY vmcnt in the main loop is vmcnt(6) at the step boundary: retires tile
// t+1's 6 loads, keeps tile t+2's 6 in flight across the barrier (m201/T3+T4).
__global__ __launch_bounds__(512, 2) void gemm_kernel(
    const int8_t* __restrict__ A,    // M x K int8 q
    const int8_t* __restrict__ B,    // N x K int8 w' = w - zero
    const float* __restrict__ scales,// N x gpr
    const float* __restrict__ tokScale, const float* __restrict__ tokZp,
    const float* __restrict__ T, const float* __restrict__ bias,
    float* __restrict__ C, int M, int N, int K, int gpr)
{
  __shared__ __align__(16) int8_t As[NSTAGE][TM * BKB];   // 3 x 32768
  __shared__ __align__(16) int8_t Bs[NSTAGE][TN * BKB];   // 3 x 16384
  __shared__ float sS[16 * TN];                           // [g][n_local], 8 KB

  const int tid   = threadIdx.x;
  const int lane  = tid & 63;
  const int wave  = tid >> 6;
  const int m0 = blockIdx.y * TM;
  const int n0 = blockIdx.x * TN;
  const int wm = (wave & 3) * 64;
  const int wn = (wave >> 2) * 64;
  const int col32 = lane & 31;
  const int khalf = lane >> 5;

  // fragment row byte-offsets and swizzle keys (k-invariant)
  int rAoff[2], kA[2], rBoff[2], kB[2];
#pragma unroll
  for (int i = 0; i < 2; ++i) {
    const int rA = wm + i * 32 + col32; rAoff[i] = rA * BKB; kA[i] = swz(rA);
    const int rB = wn + i * 32 + col32; rBoff[i] = rB * BKB; kB[i] = swz(rB);
  }

  // staging sources (pre-swizzled global chunk col; LDS dest stays linear)
  const int8_t* aSrc[4]; int aLds[4];
  const int8_t* bSrc[2]; int bLds[2];
#pragma unroll
  for (int it = 0; it < 4; ++it) {
    const int p = (it << 9) | tid;          // 2048 chunks of A-tile
    const int r = p >> 3;
    const int c = (p & 7) ^ swz(r);
    aSrc[it] = A + (size_t)(m0 + r) * K + (c << 4);
    aLds[it] = it * 8192 + wave * 1024;
  }
#pragma unroll
  for (int it = 0; it < 2; ++it) {
    const int p = (it << 9) | tid;          // 1024 chunks of B-tile
    const int r = p >> 3;
    const int c = (p & 7) ^ swz(r);
    bSrc[it] = B + (size_t)(n0 + r) * K + (c << 4);
    bLds[it] = it * 8192 + wave * 1024;
  }

  // preload scales into LDS, transposed (coalesced global read)
#pragma unroll
  for (int jj = 0; jj < (16 * TN) / 512; ++jj) {
    const int flat = tid + 512 * jj;
    const int i = flat >> 4, g = flat & 15;
    sS[g * TN + i] = scales[(size_t)(n0 + i) * gpr + g];
  }

  float accf[2][2][16];
#pragma unroll
  for (int i = 0; i < 2; ++i)
#pragma unroll
    for (int j = 0; j < 2; ++j)
#pragma unroll
      for (int r = 0; r < 16; ++r) accf[i][j][r] = 0.0f;

  i32x16 zeroC;
#pragma unroll
  for (int r = 0; r < 16; ++r) zeroC[r] = 0;
  i32x16 ai[2][2];

  const int nsteps = K / BKB;      // 32 for K=4096
  const int ngroups = nsteps / 2;  // fixup every 2 steps (G=256)

// one phase: 4 ds_read_b128, optional staging, barrier, lgkm drain, 4 MFMA, tail
#define PH(sb, kk, FIRST, STG, ENDW) do {                                      \
    const int cw = (kk) * 2 + khalf;                                           \
    const i32x4 af0 = *(const i32x4*)&As[sb][rAoff[0] + ((cw ^ kA[0]) << 4)];  \
    const i32x4 af1 = *(const i32x4*)&As[sb][rAoff[1] + ((cw ^ kA[1]) << 4)];  \
    const i32x4 bf0 = *(const i32x4*)&Bs[sb][rBoff[0] + ((cw ^ kB[0]) << 4)];  \
    const i32x4 bf1 = *(const i32x4*)&Bs[sb][rBoff[1] + ((cw ^ kB[1]) << 4)];  \
    STG;                                                                       \
    __builtin_amdgcn_s_barrier();                                              \
    asm volatile("s_waitcnt lgkmcnt(0)" ::: "memory");                         \
    __builtin_amdgcn_sched_barrier(0);                                         \
    __builtin_amdgcn_s_setprio(1);                                             \
    if (FIRST) {                                                               \
      ai[0][0] = __builtin_amdgcn_mfma_i32_32x32x32_i8(af0, bf0, zeroC, 0,0,0);\
      ai[0][1] = __builtin_amdgcn_mfma_i32_32x32x32_i8(af0, bf1, zeroC, 0,0,0);\
      ai[1][0] = __builtin_amdgcn_mfma_i32_32x32x32_i8(af1, bf0, zeroC, 0,0,0);\
      ai[1][1] = __builtin_amdgcn_mfma_i32_32x32x32_i8(af1, bf1, zeroC, 0,0,0);\
    } else {                                                                   \
      ai[0][0] = __builtin_amdgcn_mfma_i32_32x32x32_i8(af0, bf0, ai[0][0], 0,0,0);\
      ai[0][1] = __builtin_amdgcn_mfma_i32_32x32x32_i8(af0, bf1, ai[0][1], 0,0,0);\
      ai[1][0] = __builtin_amdgcn_mfma_i32_32x32x32_i8(af1, bf0, ai[1][0], 0,0,0);\
      ai[1][1] = __builtin_amdgcn_mfma_i32_32x32x32_i8(af1, bf1, ai[1][1], 0,0,0);\
    }                                                                          \
    __builtin_amdgcn_s_setprio(0);                                             \
    ENDW;                                                                      \
  } while (0)

#define SA2(i0, i1, pb, tt) do {                                               \
    async16(aSrc[i0] + (size_t)(tt) * BKB, &As[pb][aLds[i0]]);                 \
    async16(aSrc[i1] + (size_t)(tt) * BKB, &As[pb][aLds[i1]]); } while (0)
#define SB1(i0, pb, tt)                                                        \
    async16(bSrc[i0] + (size_t)(tt) * BKB, &Bs[pb][bLds[i0]])
#define NOSTG do {} while (0)

#define FIXUP(gg) do {                                                         \
    for (int j = 0; j < 2; ++j) {                                              \
      const float s = sS[(gg) * TN + wn + j * 32 + col32];                     \
      for (int i = 0; i < 2; ++i)                                              \
        for (int r = 0; r < 16; ++r)                                           \
          accf[i][j][r] += s * (float)ai[i][j][r];                             \
    }                                                                          \
  } while (0)

#define BARO  __builtin_amdgcn_s_barrier()
#define T6    do { asm volatile("s_waitcnt vmcnt(6)" ::: "memory");            \
                   __builtin_amdgcn_s_barrier(); } while (0)
#define T0    do { asm volatile("s_waitcnt vmcnt(0)" ::: "memory");            \
                   __builtin_amdgcn_s_barrier(); } while (0)
#define T6F(gg) do { FIXUP(gg);                                                \
                   asm volatile("s_waitcnt vmcnt(6)" ::: "memory");            \
                   __builtin_amdgcn_s_barrier(); } while (0)
#define TEND(gg) FIXUP(gg)

// step = 4 phases; staging of tile tt spread 2/2/1/1 across phases
#define STEP_S(sb, pb, tt, FIRST, TAIL) do {                                   \
    PH(sb, 0, FIRST, SA2(0, 1, pb, tt), BARO);                                 \
    PH(sb, 1, false, SA2(2, 3, pb, tt), BARO);                                 \
    PH(sb, 2, false, SB1(0, pb, tt),    BARO);                                 \
    PH(sb, 3, false, SB1(1, pb, tt),    TAIL);                                 \
  } while (0)
#define STEP_N(sb, FIRST, TAIL) do {                                           \
    PH(sb, 0, FIRST, NOSTG, BARO);                                             \
    PH(sb, 1, false, NOSTG, BARO);                                             \
    PH(sb, 2, false, NOSTG, BARO);                                             \
    PH(sb, 3, false, NOSTG, TAIL);                                             \
  } while (0)

  // prologue: stage tiles 0 and 1; retire tile 0's 6 loads, keep tile 1's
  // 6 in flight; lgkmcnt(0) publishes the sS ds_writes before the barrier.
#pragma unroll
  for (int it = 0; it < 4; ++it) async16(aSrc[it], &As[0][aLds[it]]);
#pragma unroll
  for (int it = 0; it < 2; ++it) async16(bSrc[it], &Bs[0][bLds[it]]);
#pragma unroll
  for (int it = 0; it < 4; ++it) async16(aSrc[it] + BKB, &As[1][aLds[it]]);
#pragma unroll
  for (int it = 0; it < 2; ++it) async16(bSrc[it] + BKB, &Bs[1][bLds[it]]);
  asm volatile("s_waitcnt vmcnt(6) lgkmcnt(0)" ::: "memory");
  __builtin_amdgcn_s_barrier();

  int b0 = 0, b1 = 1, b2 = 2;   // buffers for steps t, t+1, t+2
  for (int g = 0; g < ngroups; ++g) {
    const int t = 2 * g;
    // even step t: init acc, prefetch tile t+2 into b2
    if (t + 2 < nsteps) STEP_S(b0, b2, t + 2, true, T6);
    else                STEP_N(b0, true, T0);               // t == nsteps-2
    // odd step t+1: accumulate, prefetch tile t+3 into b0's slot, then fixup
    if (t + 3 < nsteps) STEP_S(b1, b0, t + 3, false, T6F(g));
    else                STEP_N(b1, false, TEND(g));         // t+1 == nsteps-1
    const int tmp = b0; b0 = b2; b2 = b1; b1 = tmp;
  }

#undef PH
#undef SA2
#undef SB1
#undef NOSTG
#undef FIXUP
#undef BARO
#undef T6
#undef T0
#undef T6F
#undef TEND
#undef STEP_S
#undef STEP_N

  // epilogue: C/D 32x32 layout col=lane&31, row=(reg&3)+8*(reg>>2)+4*(lane>>5)
  int   nj[2];
  float Tn[2], bn[2];
#pragma unroll
  for (int j = 0; j < 2; ++j) {
    nj[j] = n0 + wn + j * 32 + col32;
    Tn[j] = T[nj[j]];
    bn[j] = bias[nj[j]];
  }
  const int rbase = 4 * khalf;
#pragma unroll
  for (int i = 0; i < 2; ++i) {
    const int mb = m0 + wm + i * 32;
#pragma unroll
    for (int r = 0; r < 16; ++r) {
      const int m = mb + (r & 3) + 8 * (r >> 2) + rbase;
      const float ts = tokScale[m];
      const float zp = tokZp[m];
      float* crow = C + (size_t)m * N;
#pragma unroll
      for (int j = 0; j < 2; ++j)
        crow[nj[j]] = ts * (accf[i][j][r] - zp * Tn[j]) + bn[j];
    }
  }
}

// ---------- launch ----------
extern "C" void kernel_launch(void* const* d_in, const int* in_sizes, int n_in,
                              void* d_out, int out_size, void* d_ws, size_t ws_size,
                              hipStream_t stream) {
  const float* x      = (const float*)d_in[0];
  const int*   w      = (const int*)d_in[1];    // int inputs arrive as int32
  const float* scales = (const float*)d_in[2];
  const float* zeros  = (const float*)d_in[3];
  const float* bias   = (const float*)d_in[4];
  float* out = (float*)d_out;

  const int OUT = in_sizes[4];                  // 4096
  const int IN  = in_sizes[1] / OUT;            // 4096
  const int M   = in_sizes[0] / IN;             // 8192 tokens
  const int gpr = in_sizes[2] / OUT;            // 16 groups per row
  const int G   = IN / gpr;                     // 256

  int8_t* Aq = (int8_t*)d_ws;
  int8_t* Wq = Aq + (size_t)M * IN;
  float* tokScale = (float*)(Wq + (size_t)OUT * IN);
  float* tokZp = tokScale + M;
  float* T = tokZp + M;

  prep_kernel<<<M + OUT, 256, 0, stream>>>(x, Aq, tokScale, tokZp,
                                           w, scales, zeros, Wq, T, IN, M, gpr, G);
  gemm_kernel<<<dim3(OUT / TN, M / TM), 512, 0, stream>>>(
      Aq, Wq, scales, tokScale, tokZp, T, bias, out, M, OUT, IN, gpr);
}

// Round 3
// 431.601 us; speedup vs baseline: 1.1412x; 1.1412x over previous
//
#include <hip/hip_runtime.h>
#include <stdint.h>

typedef __attribute__((ext_vector_type(4))) int   i32x4;
typedef __attribute__((ext_vector_type(16))) int  i32x16;

#define TM 128
#define TN 128
#define BKB 128   // K-slice per stage, BYTES (int8 elems); group = 256 = 2*BKB

// ---------- helpers ----------

// async global -> LDS, 16 bytes per lane. LDS dest = wave-uniform base + lane*16.
__device__ __forceinline__ void async16(const void* g, void* l) {
  __builtin_amdgcn_global_load_lds(
      (__attribute__((address_space(1))) void*)g,
      (__attribute__((address_space(3))) void*)l,
      16, 0, 0);
}

__device__ __forceinline__ int swz(int r) { return (r ^ (r >> 3)) & 7; }

// ---------- fused prep kernel: WAVE-autonomous, no LDS, no __syncthreads ----------
// blocks [0, nqb)        : 4 waves x 1 token each  -> int8 Aq + tokScale/tokZp
// blocks [nqb, nqb+nwb)  : 4 waves x 1 weight row  -> Wq = w - zero, T[n]
// Rationale: the old block-per-row form put load-latency -> barrier -> LDS ->
// barrier on every block's critical path (12288 blocks, ~235us total vs ~40us
// roofline). Wave-per-row removes all intra-block sync; each wave streams.
__global__ __launch_bounds__(256) void prep_kernel(
    const float* __restrict__ x, int8_t* __restrict__ Aq,
    float* __restrict__ tokScale, float* __restrict__ tokZp,
    const int* __restrict__ W, const float* __restrict__ scales,
    const float* __restrict__ zeros, int8_t* __restrict__ Wq,
    float* __restrict__ T, int K, int M, int OUT, int gpr, int G)
{
  const int wave = threadIdx.x >> 6;
  const int lane = threadIdx.x & 63;
  const int nqb  = M >> 2;            // quant blocks (4 tokens/block)

  if ((int)blockIdx.x < nqb) {
    // ---- per-token dynamic quant: one wave per token ----
    const int token = (blockIdx.x << 2) + wave;
    if (token >= M) return;
    const float4* xin = (const float4*)(x + (size_t)token * K);

    // lane holds float4 chunks lane + 64*j  (wave instruction = 1KB contiguous)
    float4 v[16];
#pragma unroll
    for (int j = 0; j < 16; ++j) v[j] = xin[lane + 64 * j];

    float mn = v[0].x, mx = v[0].x;
#pragma unroll
    for (int j = 0; j < 16; ++j) {
      mn = fminf(mn, fminf(fminf(v[j].x, v[j].y), fminf(v[j].z, v[j].w)));
      mx = fmaxf(mx, fmaxf(fmaxf(v[j].x, v[j].y), fmaxf(v[j].z, v[j].w)));
    }
#pragma unroll
    for (int off = 32; off >= 1; off >>= 1) {
      mn = fminf(mn, __shfl_xor(mn, off));
      mx = fmaxf(mx, __shfl_xor(mx, off));
    }

    mn = fminf(mn, 0.0f);
    mx = fmaxf(mx, 0.0f);
    const float scale = fmaxf((mx - mn) / 255.0f, 1.1920929e-07f);
    float zp = -128.0f - rintf(mn / scale);   // exact division, matches ref
    zp = fminf(fmaxf(zp, -128.0f), 127.0f);
    const float rs = 1.0f / scale;

    uint32_t* dst = (uint32_t*)(Aq + (size_t)token * K);
#pragma unroll
    for (int j = 0; j < 16; ++j) {
      float e[4] = {v[j].x, v[j].y, v[j].z, v[j].w};
      uint32_t pk = 0;
#pragma unroll
      for (int i = 0; i < 4; ++i) {
        float q = rintf(e[i] * rs) + zp;      // half-to-even, like jnp.round
        q = fminf(fmaxf(q, -128.0f), 127.0f);
        pk |= ((uint32_t)(int)q & 0xFFu) << (8 * i);
      }
      dst[lane + 64 * j] = pk;
    }
    if (lane == 0) { tokScale[token] = scale; tokZp[token] = zp; }
  } else {
    // ---- weight prep: one wave per output row, streaming ----
    const int row = ((blockIdx.x - nqb) << 2) + wave;
    if (row >= OUT) return;
    const int4* wp = (const int4*)(W + (size_t)row * K);
    uint32_t* dst = (uint32_t*)(Wq + (size_t)row * K);
    const int cpg = G >> 2;                   // int4-chunks per group

    float partial = 0.0f;
#pragma unroll 4
    for (int j = 0; j < 16; ++j) {
      const int idx = lane + 64 * j;          // int4-chunk; elems idx*4..idx*4+3
      const int g = idx / cpg;                // == j for K=4096,G=256 (wave-uniform)
      const float s = scales[(size_t)row * gpr + g];
      const int zi = (int)zeros[(size_t)row * gpr + g];   // integer-valued, exact
      int4 w4 = wp[idx];
      const int a = w4.x - zi, b = w4.y - zi, c = w4.z - zi, d = w4.w - zi;
      dst[idx] = ((uint32_t)a & 0xFFu) | (((uint32_t)b & 0xFFu) << 8)
               | (((uint32_t)c & 0xFFu) << 16) | (((uint32_t)d & 0xFFu) << 24);
      partial += s * (float)(a + b + c + d);
    }
#pragma unroll
    for (int off = 32; off >= 1; off >>= 1) partial += __shfl_xor(partial, off);
    if (lane == 0) T[row] = partial;
  }
}

// ---------- kernel 2: int8 MFMA GEMM with per-group fp32 fixup (R0-proven) ----------
// out[m,n] = ts_m * ( sum_g s[n,g]*dot_g[m,n] - zp_m*T[n] ) + bias[n]
// dot_g = exact int32 sum over the 256-wide group of q[m,k]*w'[n,k].
//
// LDS swizzle: chunk position (r,c') holds global chunk (r, c'^swz(r)),
// swz(r)=(r^(r>>3))&7. Fragment reads XOR the wanted chunk col with swz(row).
__global__ __launch_bounds__(256) void gemm_kernel(
    const int8_t* __restrict__ A,    // M x K int8 q
    const int8_t* __restrict__ B,    // N x K int8 w' = w - zero
    const float* __restrict__ scales,// N x gpr
    const float* __restrict__ tokScale, const float* __restrict__ tokZp,
    const float* __restrict__ T, const float* __restrict__ bias,
    float* __restrict__ C, int M, int N, int K, int gpr)
{
  __shared__ __align__(16) int8_t As[TM * BKB];
  __shared__ __align__(16) int8_t Bs[TN * BKB];
  __shared__ float sS[16 * TN];   // [g][n_local] scales, transposed for broadcast reads

  const int tid   = threadIdx.x;
  const int lane  = tid & 63;
  const int wave  = tid >> 6;
  const int m0 = blockIdx.y * TM;
  const int n0 = blockIdx.x * TN;
  const int wm = (wave & 1) * 64;
  const int wn = (wave >> 1) * 64;
  const int col32 = lane & 31;
  const int khalf = lane >> 5;          // picks which 16-B K-chunk of the frag

  // per-fragment rows and swizzle keys (kk-invariant)
  int rA[2], kA[2], rB[2], kB[2];
#pragma unroll
  for (int i = 0; i < 2; ++i) {
    rA[i] = wm + i * 32 + col32;  kA[i] = (rA[i] ^ (rA[i] >> 3)) & 7;
    rB[i] = wn + i * 32 + col32;  kB[i] = (rB[i] ^ (rB[i] >> 3)) & 7;
  }

  // preload scales into LDS, transposed: coalesced global read
#pragma unroll
  for (int jj = 0; jj < (16 * TN) / 256; ++jj) {
    const int flat = tid + 256 * jj;
    const int i = flat >> 4, g = flat & 15;
    sS[g * TN + i] = scales[(size_t)(n0 + i) * gpr + g];
  }
  // (first __syncthreads in the k-loop orders these writes before any fixup read)

  float accf[2][2][16];
#pragma unroll
  for (int i = 0; i < 2; ++i)
#pragma unroll
    for (int j = 0; j < 2; ++j)
#pragma unroll
      for (int r = 0; r < 16; ++r) accf[i][j][r] = 0.0f;

  i32x16 zeroC;
#pragma unroll
  for (int r = 0; r < 16; ++r) zeroC[r] = 0;

  const int ngroups = K / 256;
  for (int g = 0; g < ngroups; ++g) {
    i32x16 ai[2][2];
#pragma unroll
    for (int half = 0; half < 2; ++half) {
      const int k0 = g * 256 + half * BKB;
      // stage A,B tiles: 1024 16-B chunks each, 4/thread
#pragma unroll
      for (int it = 0; it < 4; ++it) {
        const int p = (it << 8) + tid;
        const int r = p >> 3;
        const int c = (p & 7) ^ ((r ^ (r >> 3)) & 7);
        const int ldsoff = it * 4096 + wave * 1024;   // bytes, wave-uniform + lane*16
        async16(A + (size_t)(m0 + r) * K + k0 + (c << 4), &As[ldsoff]);
        async16(B + (size_t)(n0 + r) * K + k0 + (c << 4), &Bs[ldsoff]);
      }
      __syncthreads();

#pragma unroll
      for (int kk = 0; kk < 4; ++kk) {
        const int cw = kk * 2 + khalf;                // wanted 16-B chunk col
        i32x4 af[2], bf[2];
#pragma unroll
        for (int i = 0; i < 2; ++i)
          af[i] = *(const i32x4*)&As[rA[i] * BKB + ((cw ^ kA[i]) << 4)];
#pragma unroll
        for (int j = 0; j < 2; ++j)
          bf[j] = *(const i32x4*)&Bs[rB[j] * BKB + ((cw ^ kB[j]) << 4)];
#pragma unroll
        for (int i = 0; i < 2; ++i)
#pragma unroll
          for (int j = 0; j < 2; ++j) {
            if (half == 0 && kk == 0)
              ai[i][j] = __builtin_amdgcn_mfma_i32_32x32x32_i8(af[i], bf[j], zeroC, 0, 0, 0);
            else
              ai[i][j] = __builtin_amdgcn_mfma_i32_32x32x32_i8(af[i], bf[j], ai[i][j], 0, 0, 0);
          }
      }
      __syncthreads();
    }
    // per-group fixup: accf += s[n,g] * (float)dot_g
#pragma unroll
    for (int j = 0; j < 2; ++j) {
      const float s = sS[g * TN + wn + j * 32 + col32];
#pragma unroll
      for (int i = 0; i < 2; ++i)
#pragma unroll
        for (int r = 0; r < 16; ++r)
          accf[i][j][r] += s * (float)ai[i][j][r];
    }
  }

  // epilogue: C/D 32x32 layout col=lane&31, row=(reg&3)+8*(reg>>2)+4*(lane>>5)
  int   nj[2];
  float Tn[2], bn[2];
#pragma unroll
  for (int j = 0; j < 2; ++j) {
    nj[j] = n0 + wn + j * 32 + col32;
    Tn[j] = T[nj[j]];
    bn[j] = bias[nj[j]];
  }
  const int rbase = 4 * khalf;
#pragma unroll
  for (int i = 0; i < 2; ++i) {
    const int mb = m0 + wm + i * 32;
#pragma unroll
    for (int r = 0; r < 16; ++r) {
      const int m = mb + (r & 3) + 8 * (r >> 2) + rbase;
      const float ts = tokScale[m];
      const float zp = tokZp[m];
      float* crow = C + (size_t)m * N;
#pragma unroll
      for (int j = 0; j < 2; ++j)
        crow[nj[j]] = ts * (accf[i][j][r] - zp * Tn[j]) + bn[j];
    }
  }
}

// ---------- launch ----------
extern "C" void kernel_launch(void* const* d_in, const int* in_sizes, int n_in,
                              void* d_out, int out_size, void* d_ws, size_t ws_size,
                              hipStream_t stream) {
  const float* x      = (const float*)d_in[0];
  const int*   w      = (const int*)d_in[1];    // int inputs arrive as int32
  const float* scales = (const float*)d_in[2];
  const float* zeros  = (const float*)d_in[3];
  const float* bias   = (const float*)d_in[4];
  float* out = (float*)d_out;

  const int OUT = in_sizes[4];                  // 4096
  const int IN  = in_sizes[1] / OUT;            // 4096
  const int M   = in_sizes[0] / IN;             // 8192 tokens
  const int gpr = in_sizes[2] / OUT;            // 16 groups per row
  const int G   = IN / gpr;                     // 256

  // workspace: Aq int8 (M*IN), Wq int8 (OUT*IN), tokScale f32 (M), tokZp f32 (M), T f32 (OUT)
  int8_t* Aq = (int8_t*)d_ws;
  int8_t* Wq = Aq + (size_t)M * IN;
  float* tokScale = (float*)(Wq + (size_t)OUT * IN);
  float* tokZp = tokScale + M;
  float* T = tokZp + M;

  const int nqb = M >> 2;                       // 4 tokens per block (wave each)
  const int nwb = (OUT + 3) >> 2;               // 4 rows per block (wave each)
  prep_kernel<<<nqb + nwb, 256, 0, stream>>>(x, Aq, tokScale, tokZp,
                                             w, scales, zeros, Wq, T,
                                             IN, M, OUT, gpr, G);
  gemm_kernel<<<dim3(OUT / TN, M / TM), 256, 0, stream>>>(
      Aq, Wq, scales, tokScale, tokZp, T, bias, out, M, OUT, IN, gpr);
}